// Round 1
// baseline (721.331 us; speedup 1.0000x reference)
//
#include <hip/hip_runtime.h>

// IBRNet aggregator, fully fused, fp32.
// Layout facts (all fp32):
//  features   (2,8,32,32^3)   idx ((b*8+n)*32+c)*32768+v
//  mask/depth (2,8,1,32^3)    idx (b*8+n)*32768+v
//  voxel_dir  (2,8,3,32^3)    idx ((b*8+n)*3+d)*32768+v
//  weights row-major [o][i]
//  out        (2,32,32^3)     idx (b*32+c)*32768+v
//
// One wave (64 lanes) = 8 voxels x 8 views. n = lane>>3, vsub = lane&7.
// Cross-view reductions = shfl_xor butterflies over lanemask {8,16,32}.
// MLPs: inputs in registers (static unroll), output index o is a dynamic
// wave-uniform loop -> weight rows become wide scalar loads; hidden vectors
// round-trip through a private per-lane LDS column for dynamic indexing.

#define G3 32768

__device__ __forceinline__ float eluf(float x) {
    return x > 0.0f ? x : __expf(x) - 1.0f;
}
__device__ __forceinline__ float sigmoidf(float x) {
    return 1.0f / (1.0f + __expf(-x));
}
__device__ __forceinline__ float red8(float v) {
    v += __shfl_xor(v, 8, 64);
    v += __shfl_xor(v, 16, 64);
    v += __shfl_xor(v, 32, 64);
    return v;
}

// 4-chain dot of a uniform weight row (scalar loads) with a register vector.
template <int K>
__device__ __forceinline__ float dotrow(const float* __restrict__ row,
                                        const float (&x)[K]) {
    float a0 = 0.f, a1 = 0.f, a2 = 0.f, a3 = 0.f;
#pragma unroll
    for (int c = 0; c < K; c += 4) {
        a0 += row[c + 0] * x[c + 0];
        a1 += row[c + 1] * x[c + 1];
        a2 += row[c + 2] * x[c + 2];
        a3 += row[c + 3] * x[c + 3];
    }
    return (a0 + a1) + (a2 + a3);
}

__global__ __launch_bounds__(64, 2) void ibr_kernel(
    const float* __restrict__ features, const float* __restrict__ mask,
    const float* __restrict__ vdepth, const float* __restrict__ vdir,
    const float* __restrict__ rde_w1, const float* __restrict__ rde_b1,
    const float* __restrict__ rde_w2, const float* __restrict__ rde_b2,
    const float* __restrict__ base_w1, const float* __restrict__ base_b1,
    const float* __restrict__ base_w2, const float* __restrict__ base_b2,
    const float* __restrict__ vis_w1, const float* __restrict__ vis_b1,
    const float* __restrict__ vis_w2, const float* __restrict__ vis_b2,
    const float* __restrict__ vis2_w1, const float* __restrict__ vis2_b1,
    const float* __restrict__ vis2_w2, const float* __restrict__ vis2_b2,
    const float* __restrict__ stat_w, const float* __restrict__ stat_b,
    float* __restrict__ out) {
    __shared__ float scratch[64 * 64];  // [row][lane], 16 KB, per-lane columns

    const int lane = threadIdx.x;  // 0..63
    const int n = lane >> 3;       // view 0..7
    const int vsub = lane & 7;
    const int blk = blockIdx.x;    // 0..8191
    const int b = blk >> 12;       // 4096 blocks per batch
    const int v = ((blk & 4095) << 3) + vsub;
    const int bn = b * 8 + n;

    // ---------------- phase A: rde MLP, feats, mask-weighted mean/var ------
    const float m = mask[bn * G3 + v];
    float r0 = vdir[(bn * 3 + 0) * G3 + v];
    float r1 = vdir[(bn * 3 + 1) * G3 + v];
    float r2 = vdir[(bn * 3 + 2) * G3 + v];
    float r3 = vdepth[bn * G3 + v];

    float h16[16];
#pragma unroll
    for (int o = 0; o < 16; ++o) {
        float a = rde_b1[o] + rde_w1[o * 4 + 0] * r0 + rde_w1[o * 4 + 1] * r1 +
                  rde_w1[o * 4 + 2] * r2 + rde_w1[o * 4 + 3] * r3;
        h16[o] = eluf(a);
    }
    float f[32];
#pragma unroll
    for (int o = 0; o < 32; ++o) {
        float a = rde_b2[o];
#pragma unroll
        for (int c = 0; c < 16; ++c) a += rde_w2[o * 16 + c] * h16[c];
        f[o] = eluf(a) + features[(bn * 32 + o) * G3 + v];
    }

    const float msum = red8(m);
    const float wt = m / (msum + 1e-8f);

    float mean[32], var[32];
#pragma unroll
    for (int c = 0; c < 32; ++c) mean[c] = red8(wt * f[c]);
#pragma unroll
    for (int c = 0; c < 32; ++c) {
        float d = f[c] - mean[c];
        var[c] = red8(wt * d * d);
    }

    // ---------------- base MLP: 96 -> 64 -> 32 -----------------------------
#pragma unroll 2
    for (int o = 0; o < 64; ++o) {
        const float* row = base_w1 + o * 96;
        float a = dotrow<32>(row, mean) + dotrow<32>(row + 32, var) +
                  dotrow<32>(row + 64, f) + base_b1[o];
        scratch[o * 64 + lane] = eluf(a);
    }
    float h[64];
#pragma unroll
    for (int c = 0; c < 64; ++c) h[c] = scratch[c * 64 + lane];

#pragma unroll 2
    for (int o = 0; o < 32; ++o) {
        const float* row = base_w2 + o * 64;
        scratch[o * 64 + lane] = eluf(dotrow<64>(row, h) + base_b2[o]);
    }
    float x[32];
#pragma unroll
    for (int c = 0; c < 32; ++c) x[c] = scratch[c * 64 + lane];

    // ---------------- vis MLP: (x*wt) 32 -> 32 -> 33 -----------------------
    float xin[32];
#pragma unroll
    for (int c = 0; c < 32; ++c) xin[c] = x[c] * wt;
#pragma unroll 2
    for (int o = 0; o < 32; ++o) {
        const float* row = vis_w1 + o * 32;
        scratch[o * 64 + lane] = eluf(dotrow<32>(row, xin) + vis_b1[o]);
    }
    float hv[32];
#pragma unroll
    for (int c = 0; c < 32; ++c) hv[c] = scratch[c * 64 + lane];
#pragma unroll 2
    for (int o = 0; o < 33; ++o) {
        const float* row = vis_w2 + o * 32;
        scratch[o * 64 + lane] = eluf(dotrow<32>(row, hv) + vis_b2[o]);
    }
#pragma unroll
    for (int c = 0; c < 32; ++c) x[c] += scratch[c * 64 + lane];
    const float visn = sigmoidf(scratch[32 * 64 + lane]) * m;

    // ---------------- vis2 MLP: (x*visn) 32 -> 32 -> 1 ---------------------
#pragma unroll
    for (int c = 0; c < 32; ++c) xin[c] = x[c] * visn;
#pragma unroll 2
    for (int o = 0; o < 32; ++o) {
        const float* row = vis2_w1 + o * 32;
        scratch[o * 64 + lane] = eluf(dotrow<32>(row, xin) + vis2_b1[o]);
    }
#pragma unroll
    for (int c = 0; c < 32; ++c) hv[c] = scratch[c * 64 + lane];
    const float visv = sigmoidf(dotrow<32>(vis2_w2, hv) + vis2_b2[0]) * m;

    // ---------------- phase C: vis-weighted mean/var + stat conv -----------
    const float b0 = red8(visv);
    const float inv = 1.0f / (b0 + 1e-8f);
    const float wt2 = visv * inv;
    const float wm = b0 * inv * 0.125f;

    float mean2[32], var2[32];
#pragma unroll
    for (int c = 0; c < 32; ++c) mean2[c] = red8(wt2 * x[c]);
#pragma unroll
    for (int c = 0; c < 32; ++c) {
        float d = x[c] - mean2[c];
        var2[c] = red8(wt2 * d * d);
    }

#pragma unroll 2
    for (int o = 0; o < 32; ++o) {
        const float* row = stat_w + o * 65;
        float a = dotrow<32>(row, mean2) + dotrow<32>(row + 32, var2) +
                  row[64] * wm + stat_b[o];
        float r = eluf(a);
        // lanes for view n store output channels [4n, 4n+4) of their voxel
        if ((o >> 2) == n) out[(b * 32 + o) * G3 + v] = r;
    }
}

extern "C" void kernel_launch(void* const* d_in, const int* in_sizes, int n_in,
                              void* d_out, int out_size, void* d_ws,
                              size_t ws_size, hipStream_t stream) {
    const float* features = (const float*)d_in[0];
    const float* mask = (const float*)d_in[1];
    const float* vdepth = (const float*)d_in[2];
    const float* vdir = (const float*)d_in[3];
    const float* rde_w1 = (const float*)d_in[4];
    const float* rde_b1 = (const float*)d_in[5];
    const float* rde_w2 = (const float*)d_in[6];
    const float* rde_b2 = (const float*)d_in[7];
    const float* base_w1 = (const float*)d_in[8];
    const float* base_b1 = (const float*)d_in[9];
    const float* base_w2 = (const float*)d_in[10];
    const float* base_b2 = (const float*)d_in[11];
    const float* vis_w1 = (const float*)d_in[12];
    const float* vis_b1 = (const float*)d_in[13];
    const float* vis_w2 = (const float*)d_in[14];
    const float* vis_b2 = (const float*)d_in[15];
    const float* vis2_w1 = (const float*)d_in[16];
    const float* vis2_b1 = (const float*)d_in[17];
    const float* vis2_w2 = (const float*)d_in[18];
    const float* vis2_b2 = (const float*)d_in[19];
    const float* stat_w = (const float*)d_in[20];
    const float* stat_b = (const float*)d_in[21];

    // grid: 2 batches * 32768 voxels / 8 voxels-per-block = 8192 blocks
    ibr_kernel<<<8192, 64, 0, stream>>>(
        features, mask, vdepth, vdir, rde_w1, rde_b1, rde_w2, rde_b2, base_w1,
        base_b1, base_w2, base_b2, vis_w1, vis_b1, vis_w2, vis_b2, vis2_w1,
        vis2_b1, vis2_w2, vis2_b2, stat_w, stat_b, (float*)d_out);
}